// Round 8
// baseline (2348.338 us; speedup 1.0000x reference)
//
#include <hip/hip_runtime.h>

#define NN 512
#define NM1 511
#define PCT(r, j) pcT[(r) * 13 + (j)]

// X-macro helpers: T4x16(X) expands X(K,M) for K=0..3, M=0..15
#define T16(X, K) X(K,0) X(K,1) X(K,2) X(K,3) X(K,4) X(K,5) X(K,6) X(K,7) \
                  X(K,8) X(K,9) X(K,10) X(K,11) X(K,12) X(K,13) X(K,14) X(K,15)
#define T4x16(X) T16(X,0) T16(X,1) T16(X,2) T16(X,3)
#define T16S(X) X(0) X(1) X(2) X(3) X(4) X(5) X(6) X(7) \
                X(8) X(9) X(10) X(11) X(12) X(13) X(14) X(15)

// One block per matrix (1024 blocks). Blocked LU, panel r=8, implicit partial
// pivoting. Tile: rows {L,L+64,L+128,L+192} x cols [16w,16w+16) as 64 named
// scalars. r7 post-mortem: named scalars alone (r6/r7) still spilled because
// the DEFAULT allocator heuristic targets 8 waves/EU (64-reg total budget).
// r2 proved the tile fits at a 128-reg budget; r4 proved waves_per_eu(4,4) +
// LDS>80KiB takes effect (SGPR 48->112). This round combines: good tile form
// (named scalars, r6) + forced 4-waves/EU 128-reg budget (r4 env) + dead4
// pivot-history mask (r7, saves 7 regs vs parr[8]) + pcrow reg cache (r6).
__global__ __attribute__((amdgpu_waves_per_eu(4, 4))) __launch_bounds__(1024)
void det_lu_kernel(
    const float* __restrict__ x,
    const float* __restrict__ F,
    float* __restrict__ out) {
  __shared__ __align__(16) float pcT[256 * 13];   // panel cols, row-major pad 13
  __shared__ __align__(16) float lbuf[8 * 256];   // multipliers per step
  __shared__ __align__(16) float Ubuf[8 * 260];   // final pivot rows (pad 260)
  __shared__ __align__(16) float araw[8 * 260];   // raw pivot rows
  __shared__ float livef[256];
  __shared__ int   perm[256];
  __shared__ int   upbuf[256];
  __shared__ int   dnbuf[256];
  __shared__ int   wavecnt[8];
  __shared__ int   totinv;
  __shared__ float ldspad[10000];   // occupancy limiter: LDS > 80KiB -> 1 blk/CU

  const int tid = threadIdx.x;
  const int L   = tid & 63;       // lane
  const int w   = tid >> 6;       // wave

  const float* xrow = x + (size_t)blockIdx.x * NN;

  // keep ldspad referenced (opaque never-true condition)
  if ((int)blockIdx.x < 0) ((volatile float*)ldspad)[tid] = 1.0f;

  // ---- rank the +/-1 pattern: up = x>0 positions, dn = x<=0 positions
  bool pos = false;
  unsigned long long mask = 0;
  if (tid < NN) {
    float xv = xrow[tid];
    pos = xv > 0.0f;
    mask = __ballot(pos);
    if (L == 0) wavecnt[w] = __popcll(mask);
  }
  if (tid == 0) totinv = 0;
  if (tid < 256) livef[tid] = 1.0f;
  __syncthreads();
  if (tid < NN) {
    int base = 0;
    for (int i = 0; i < w; i++) base += wavecnt[i];
    int pbelow = __popcll(mask & ((1ull << L) - 1ull));
    if (pos) upbuf[base + pbelow] = tid;
    else     dnbuf[(64 * w - base) + (L - pbelow)] = tid;
  }
  __syncthreads();

  // ---- gather tile into 64 named scalars: aK_M = sub[L+64K][16w+M]
#define DECLC(M) const int cg##M = dnbuf[16 * w + (M)];
  T16S(DECLC)
  const int rg0 = upbuf[L];
  const int rg1 = upbuf[L + 64];
  const int rg2 = upbuf[L + 128];
  const int rg3 = upbuf[L + 192];
#define DECLA(K, M)                                                         \
  float a##K##_##M = (cg##M == rg##K)                                       \
      ? 0.0f                                                                \
      : F[(size_t)rg##K * NM1 + cg##M - (cg##M > rg##K ? 1 : 0)];
  T4x16(DECLA)

  // ---- seed panel 0: wave 0 writes PCT[row][0..7]
  if (w == 0) {
#define S0(K, M) if ((M) < 8) PCT(L + 64 * (K), (M)) = a##K##_##M;
    T4x16(S0)
  }
  double det = 1.0;
  bool mylive = true;          // row-thread's own-row liveness (tid>=768)
  __syncthreads();

  // ---- panel loop
  for (int P = 0; P < 32; P++) {
    unsigned dead4 = 0u;   // bit k: my row L+64k pivoted in THIS panel
                           // (prior panels: PCT seeded to 0 via livef)

    // row-threads cache their panel row in registers
    float pcrow[8];
    if (tid >= 768) {
      const int rr = tid - 768;
#pragma unroll
      for (int j = 0; j < 8; j++) pcrow[j] = PCT(rr, j);
    }

    // -------- 8 column-steps, ONE barrier each --------
#pragma unroll
    for (int s = 0; s < 8; s++) {
      // search: all threads, redundant
      unsigned key = 0u;
#pragma unroll
      for (int k = 0; k < 4; k++) {
        int rho = L + 64 * k;
        float v = PCT(rho, s);
        unsigned b = __float_as_uint(fabsf(v)) & 0xFFFFFF00u;
        unsigned kq = ((dead4 >> k) & 1u) ? 0u : (b | (unsigned)rho);
        key = key > kq ? key : kq;
      }
#pragma unroll
      for (int off = 32; off; off >>= 1) {
        unsigned o = (unsigned)__shfl_xor((int)key, off);
        key = key > o ? key : o;
      }
      const int p = (int)(key & 255u);
      if ((p & 63) == L) dead4 |= 1u << (p >> 6);
      const float piv = PCT(p, s);   // nobody writes col s this step
      det *= (double)piv;

      if (tid >= 768) {              // row-thread work
        const int rr = tid - 768;
        const float invp = 1.0f / piv;
        float l = (mylive && rr != p) ? pcrow[s] * invp : 0.0f;
        lbuf[s * 256 + rr] = l;
        if (rr == p) { mylive = false; livef[rr] = 0.0f; perm[P * 8 + s] = p; }
#pragma unroll
        for (int j = s + 1; j < 8; j++) {
          float uj = PCT(p, j);      // pivot row: benign same-value rewrite
          pcrow[j] = fmaf(-l, uj, pcrow[j]);
          PCT(rr, j) = pcrow[j];
        }
      }
      // raw pivot-row stash for the U-solve (live-col waves only)
      if ((2 * w + 1 > P) && L == (p & 63)) {
        const int kp = p >> 6;
        const int sb = s * 260 + 16 * w;
#define ST(K, M) if (kp == (K)) araw[sb + (M)] = a##K##_##M;
        T4x16(ST)
      }
      __syncthreads();
    }

    // -------- U-solve: U[t][j] = araw[t][j] - sum_{s<t} l_s[p_t]*U[s][j]
    if (tid < 256) {
      const int j = tid;
      float u[8];
#pragma unroll
      for (int t = 0; t < 8; t++) {
        int pt = perm[P * 8 + t];
        float acc = araw[t * 260 + j];
#pragma unroll
        for (int s2 = 0; s2 < t; s2++) acc = fmaf(-lbuf[s2 * 256 + pt], u[s2], acc);
        u[t] = acc;
        Ubuf[t * 260 + j] = acc;
      }
    }
    __syncthreads();

    // -------- rank-8 trailing update (quad at a time) + seed next panel ----
#define TUROW(K, A, B, C, D)                                                \
    a##K##_##A = fmaf(-lk##K, uq.x, a##K##_##A);                            \
    a##K##_##B = fmaf(-lk##K, uq.y, a##K##_##B);                            \
    a##K##_##C = fmaf(-lk##K, uq.z, a##K##_##C);                            \
    a##K##_##D = fmaf(-lk##K, uq.w, a##K##_##D);
#define TUQ(A, B, C, D)                                                     \
    TUROW(0, A, B, C, D) TUROW(1, A, B, C, D)                               \
    TUROW(2, A, B, C, D) TUROW(3, A, B, C, D)
    if (2 * w + 1 > P) {
      for (int t = 0; t < 8; t++) {
        const int lb = t * 256 + L;
        const float lk0 = lbuf[lb];
        const float lk1 = lbuf[lb + 64];
        const float lk2 = lbuf[lb + 128];
        const float lk3 = lbuf[lb + 192];
        const float* ub = &Ubuf[t * 260 + 16 * w];
        { const float4 uq = *reinterpret_cast<const float4*>(ub + 0);
          TUQ(0, 1, 2, 3) }
        { const float4 uq = *reinterpret_cast<const float4*>(ub + 4);
          TUQ(4, 5, 6, 7) }
        { const float4 uq = *reinterpret_cast<const float4*>(ub + 8);
          TUQ(8, 9, 10, 11) }
        { const float4 uq = *reinterpret_cast<const float4*>(ub + 12);
          TUQ(12, 13, 14, 15) }
      }
    }
    {
      const int wstar = (P + 1) >> 1, h = (P + 1) & 1;
      if (P < 31 && w == wstar) {
        const float lv0 = livef[L];
        const float lv1 = livef[L + 64];
        const float lv2 = livef[L + 128];
        const float lv3 = livef[L + 192];
        if (h == 0) {
#define SE0(K, M) if ((M) < 8) PCT(L + 64 * (K), (M)) = a##K##_##M * lv##K;
          T4x16(SE0)
        } else {
#define SE1(K, M) if ((M) >= 8) PCT(L + 64 * (K), (M) - 8) = a##K##_##M * lv##K;
          T4x16(SE1)
        }
      }
    }
    __syncthreads();
  }

  // ---- permutation parity via parallel inversion count (verified in r2)
  int myinv = 0;
  {
    const int i0 = tid & 255;
    const int cbase = (tid >> 8) * 64;
    const int pi = perm[i0];
#pragma unroll 8
    for (int j = 0; j < 64; j++) {
      int jj = cbase + j;
      if (jj > i0 && perm[jj] < pi) myinv++;
    }
  }
#pragma unroll
  for (int off = 32; off; off >>= 1) myinv += __shfl_xor(myinv, off);
  if (L == 0) atomicAdd(&totinv, myinv);
  __syncthreads();
  if (tid == 0) out[blockIdx.x] = (float)((totinv & 1) ? -det : det);
}

extern "C" void kernel_launch(void* const* d_in, const int* in_sizes, int n_in,
                              void* d_out, int out_size, void* d_ws, size_t ws_size,
                              hipStream_t stream) {
  const float* x = (const float*)d_in[0];   // (1024, 512) fp32
  const float* F = (const float*)d_in[1];   // (512*512-512,) fp32
  float* out = (float*)d_out;               // (1024,) fp32
  const int B = out_size;                   // 1024
  hipLaunchKernelGGL(det_lu_kernel, dim3(B), dim3(1024), 0, stream, x, F, out);
}

// Round 9
// 1391.839 us; speedup vs baseline: 1.6872x; 1.6872x over previous
//
#include <hip/hip_runtime.h>

#define NN 512
#define NM1 511
#define PCT(r, j) pcT[(r) * 13 + (j)]

// X-macros: T4x32(X) expands X(K,M) for K=0..3 (row group), M=0..31 (col)
#define T32(X, K) X(K,0) X(K,1) X(K,2) X(K,3) X(K,4) X(K,5) X(K,6) X(K,7) \
  X(K,8) X(K,9) X(K,10) X(K,11) X(K,12) X(K,13) X(K,14) X(K,15) \
  X(K,16) X(K,17) X(K,18) X(K,19) X(K,20) X(K,21) X(K,22) X(K,23) \
  X(K,24) X(K,25) X(K,26) X(K,27) X(K,28) X(K,29) X(K,30) X(K,31)
#define T4x32(X) T32(X,0) T32(X,1) T32(X,2) T32(X,3)
#define T32S(X) X(0) X(1) X(2) X(3) X(4) X(5) X(6) X(7) \
  X(8) X(9) X(10) X(11) X(12) X(13) X(14) X(15) \
  X(16) X(17) X(18) X(19) X(20) X(21) X(22) X(23) \
  X(24) X(25) X(26) X(27) X(28) X(29) X(30) X(31)

// One block per matrix (1024 blocks), 512 THREADS (8 waves). r8 post-mortem:
// a 16-wave workgroup is hard-capped at 128 regs/thread (512-reg SIMD file /
// 4 waves per SIMD) and the working set (~150) cannot fit -> unavoidable
// spill. 8-wave workgroup + LDS>80KiB (1 block/CU) -> 2 waves/SIMD -> 256-reg
// budget. Tile: rows {L,L+64,L+128,L+192} x cols [32w,32w+32) as 128 named
// scalars. Blocked LU, panel r=8, implicit partial pivoting (algorithm
// verified r2-r8, absmax 0.0039). Row-threads tid<256 do panel column-steps
// with LDS RMW (r6 form, no pcrow array); s-loop NOT unrolled.
__global__ __launch_bounds__(512, 2) void det_lu_kernel(
    const float* __restrict__ x,
    const float* __restrict__ F,
    float* __restrict__ out) {
  __shared__ __align__(16) float pcT[256 * 13];   // panel cols, row-major pad 13
  __shared__ __align__(16) float lbuf[8 * 256];   // multipliers per step
  __shared__ __align__(16) float Ubuf[8 * 260];   // final pivot rows (pad 260)
  __shared__ __align__(16) float araw[8 * 260];   // raw pivot rows
  __shared__ float livef[256];
  __shared__ int   perm[256];
  __shared__ int   upbuf[256];
  __shared__ int   dnbuf[256];
  __shared__ int   wavecnt[8];
  __shared__ int   totinv;
  __shared__ float ldspad[10240];   // LDS > 80KiB -> exactly 1 block/CU

  const int tid = threadIdx.x;
  const int L   = tid & 63;       // lane
  const int w   = tid >> 6;       // wave, owns cols [32w, 32w+32)

  const float* xrow = x + (size_t)blockIdx.x * NN;

  // keep ldspad referenced (opaque never-true condition)
  if ((int)blockIdx.x < 0) ((volatile float*)ldspad)[tid] = 1.0f;

  // ---- rank the +/-1 pattern: up = x>0 positions, dn = x<=0 positions
  float xv = xrow[tid];            // 512 threads == NN
  bool pos = xv > 0.0f;
  unsigned long long mask = __ballot(pos);
  if (L == 0) wavecnt[w] = __popcll(mask);
  if (tid == 0) totinv = 0;
  if (tid < 256) livef[tid] = 1.0f;
  __syncthreads();
  {
    int base = 0;
    for (int i = 0; i < w; i++) base += wavecnt[i];
    int pbelow = __popcll(mask & ((1ull << L) - 1ull));
    if (pos) upbuf[base + pbelow] = tid;
    else     dnbuf[(64 * w - base) + (L - pbelow)] = tid;
  }
  __syncthreads();

  // ---- gather tile into 128 named scalars: aK_M = sub[L+64K][32w+M]
#define DECLC(M) const int cg##M = dnbuf[32 * w + (M)];
  T32S(DECLC)
  const int rg0 = upbuf[L];
  const int rg1 = upbuf[L + 64];
  const int rg2 = upbuf[L + 128];
  const int rg3 = upbuf[L + 192];
#define DECLA(K, M)                                                         \
  float a##K##_##M = (cg##M == rg##K)                                       \
      ? 0.0f                                                                \
      : F[(size_t)rg##K * NM1 + cg##M - (cg##M > rg##K ? 1 : 0)];
  T4x32(DECLA)

  // ---- seed panel 0: wave 0 writes PCT[row][0..7]
  if (w == 0) {
#define S0(K, M) if ((M) < 8) PCT(L + 64 * (K), (M)) = a##K##_##M;
    T4x32(S0)
  }
  double det = 1.0;
  bool mylive = true;          // row-thread's own-row liveness (tid<256)
  __syncthreads();

  // ---- panel loop
#pragma unroll 1
  for (int P = 0; P < 32; P++) {
    unsigned dead4 = 0u;   // bit k: row L+64k pivoted in THIS panel
                           // (prior panels: PCT seeded to 0 via livef)

    // -------- 8 column-steps, ONE barrier each --------
#pragma unroll 1
    for (int s = 0; s < 8; s++) {
      // search: all threads (incl. retired waves — det must reach tid 0)
      unsigned key = 0u;
#pragma unroll
      for (int k = 0; k < 4; k++) {
        int rho = L + 64 * k;
        float v = PCT(rho, s);
        unsigned b = __float_as_uint(fabsf(v)) & 0xFFFFFF00u;
        unsigned kq = ((dead4 >> k) & 1u) ? 0u : (b | (unsigned)rho);
        key = key > kq ? key : kq;
      }
#pragma unroll
      for (int off = 32; off; off >>= 1) {
        unsigned o = (unsigned)__shfl_xor((int)key, off);
        key = key > o ? key : o;
      }
      const int p = (int)(key & 255u);
      if ((p & 63) == L) dead4 |= 1u << (p >> 6);
      const float piv = PCT(p, s);   // nobody writes col s this step
      det *= (double)piv;

      if (tid < 256) {               // row-thread work (LDS RMW form)
        const int rr = tid;
        const float invp = 1.0f / piv;
        const float ps = PCT(rr, s);
        float l = (mylive && rr != p) ? ps * invp : 0.0f;
        lbuf[s * 256 + rr] = l;
        if (rr == p) { mylive = false; livef[rr] = 0.0f; perm[P * 8 + s] = p; }
        for (int j = s + 1; j < 8; j++) {
          float uj = PCT(p, j);      // pivot row: benign same-value rewrite
          PCT(rr, j) = fmaf(-l, uj, PCT(rr, j));
        }
      }
      // raw pivot-row stash for the U-solve (live-col waves only)
      if ((4 * w + 3 > P) && L == (p & 63)) {
        const int kp = p >> 6;       // wave-uniform scalar
        const int sb = s * 260 + 32 * w;
#define ST(K, M) if (kp == (K)) araw[sb + (M)] = a##K##_##M;
        T4x32(ST)
      }
      __syncthreads();
    }

    // -------- U-solve: U[t][j] = araw[t][j] - sum_{s<t} l_s[p_t]*U[s][j]
    if (tid < 256) {
      const int j = tid;
      float u[8];
#pragma unroll
      for (int t = 0; t < 8; t++) {
        int pt = perm[P * 8 + t];
        float acc = araw[t * 260 + j];
#pragma unroll
        for (int s2 = 0; s2 < t; s2++) acc = fmaf(-lbuf[s2 * 256 + pt], u[s2], acc);
        u[t] = acc;
        Ubuf[t * 260 + j] = acc;
      }
    }
    __syncthreads();

    // -------- rank-8 trailing update (quad at a time) + seed next panel ----
#define TUROW(K, A, B, C, D)                                                \
    a##K##_##A = fmaf(-lk##K, uq.x, a##K##_##A);                            \
    a##K##_##B = fmaf(-lk##K, uq.y, a##K##_##B);                            \
    a##K##_##C = fmaf(-lk##K, uq.z, a##K##_##C);                            \
    a##K##_##D = fmaf(-lk##K, uq.w, a##K##_##D);
#define TUQ(A, B, C, D)                                                     \
    TUROW(0, A, B, C, D) TUROW(1, A, B, C, D)                               \
    TUROW(2, A, B, C, D) TUROW(3, A, B, C, D)
    if (4 * w + 3 > P) {
#pragma unroll 1
      for (int t = 0; t < 8; t++) {
        const int lb = t * 256 + L;
        const float lk0 = lbuf[lb];
        const float lk1 = lbuf[lb + 64];
        const float lk2 = lbuf[lb + 128];
        const float lk3 = lbuf[lb + 192];
        const float* ub = &Ubuf[t * 260 + 32 * w];
        { const float4 uq = *reinterpret_cast<const float4*>(ub + 0);
          TUQ(0, 1, 2, 3) }
        { const float4 uq = *reinterpret_cast<const float4*>(ub + 4);
          TUQ(4, 5, 6, 7) }
        { const float4 uq = *reinterpret_cast<const float4*>(ub + 8);
          TUQ(8, 9, 10, 11) }
        { const float4 uq = *reinterpret_cast<const float4*>(ub + 12);
          TUQ(12, 13, 14, 15) }
        { const float4 uq = *reinterpret_cast<const float4*>(ub + 16);
          TUQ(16, 17, 18, 19) }
        { const float4 uq = *reinterpret_cast<const float4*>(ub + 20);
          TUQ(20, 21, 22, 23) }
        { const float4 uq = *reinterpret_cast<const float4*>(ub + 24);
          TUQ(24, 25, 26, 27) }
        { const float4 uq = *reinterpret_cast<const float4*>(ub + 28);
          TUQ(28, 29, 30, 31) }
      }
    }
    {
      const int wstar = (P + 1) >> 2, h = (P + 1) & 3;
      if (P < 31 && w == wstar) {
        const float lv0 = livef[L];
        const float lv1 = livef[L + 64];
        const float lv2 = livef[L + 128];
        const float lv3 = livef[L + 192];
#define SEa(K, M) if ((M) < 8)                PCT(L + 64*(K), (M))      = a##K##_##M * lv##K;
#define SEb(K, M) if ((M) >= 8 && (M) < 16)   PCT(L + 64*(K), (M) - 8)  = a##K##_##M * lv##K;
#define SEc(K, M) if ((M) >= 16 && (M) < 24)  PCT(L + 64*(K), (M) - 16) = a##K##_##M * lv##K;
#define SEd(K, M) if ((M) >= 24)              PCT(L + 64*(K), (M) - 24) = a##K##_##M * lv##K;
        if (h == 0)      { T4x32(SEa) }
        else if (h == 1) { T4x32(SEb) }
        else if (h == 2) { T4x32(SEc) }
        else             { T4x32(SEd) }
      }
    }
    __syncthreads();
  }

  // ---- permutation parity via parallel inversion count (512-thread map)
  int myinv = 0;
  {
    const int i0 = tid & 255;
    const int cbase = (tid >> 8) * 128;
    const int pi = perm[i0];
#pragma unroll 8
    for (int j = 0; j < 128; j++) {
      int jj = cbase + j;
      if (jj > i0 && perm[jj] < pi) myinv++;
    }
  }
#pragma unroll
  for (int off = 32; off; off >>= 1) myinv += __shfl_xor(myinv, off);
  if (L == 0) atomicAdd(&totinv, myinv);
  __syncthreads();
  if (tid == 0) out[blockIdx.x] = (float)((totinv & 1) ? -det : det);
}

extern "C" void kernel_launch(void* const* d_in, const int* in_sizes, int n_in,
                              void* d_out, int out_size, void* d_ws, size_t ws_size,
                              hipStream_t stream) {
  const float* x = (const float*)d_in[0];   // (1024, 512) fp32
  const float* F = (const float*)d_in[1];   // (512*512-512,) fp32
  float* out = (float*)d_out;               // (1024,) fp32
  const int B = out_size;                   // 1024
  hipLaunchKernelGGL(det_lu_kernel, dim3(B), dim3(512), 0, stream, x, F, out);
}

// Round 10
// 1289.089 us; speedup vs baseline: 1.8217x; 1.0797x over previous
//
#include <hip/hip_runtime.h>

#define NN 512
#define NM1 511
#define PCT(r, j) pcT[(r) * 13 + (j)]

// X-macros: T4x32(X) expands X(K,M) for K=0..3 (row group), M=0..31 (col)
#define T32(X, K) X(K,0) X(K,1) X(K,2) X(K,3) X(K,4) X(K,5) X(K,6) X(K,7) \
  X(K,8) X(K,9) X(K,10) X(K,11) X(K,12) X(K,13) X(K,14) X(K,15) \
  X(K,16) X(K,17) X(K,18) X(K,19) X(K,20) X(K,21) X(K,22) X(K,23) \
  X(K,24) X(K,25) X(K,26) X(K,27) X(K,28) X(K,29) X(K,30) X(K,31)
#define T4x32(X) T32(X,0) T32(X,1) T32(X,2) T32(X,3)
#define T32S(X) X(0) X(1) X(2) X(3) X(4) X(5) X(6) X(7) \
  X(8) X(9) X(10) X(11) X(12) X(13) X(14) X(15) \
  X(16) X(17) X(18) X(19) X(20) X(21) X(22) X(23) \
  X(24) X(25) X(26) X(27) X(28) X(29) X(30) X(31)
#define P8(X, K) X(K,0) X(K,1) X(K,2) X(K,3) X(K,4) X(K,5) X(K,6) X(K,7)
#define P4x8(X) P8(X,0) P8(X,1) P8(X,2) P8(X,3)

// One block per matrix (1024 blocks), 512 threads (8 waves), 1 block/CU via
// LDS pad -> 256-reg/thread budget (r9: no spill). Blocked LU, panel r=8.
// r10: panel factorization moved fully IN-REGISTER, redundantly on all waves
// (prow = 32 regs: lane's 4 rows x 8 panel cols). Argmax = in-lane max +
// shfl_xor reduce; pivot row broadcast via __shfl; NO LDS/barrier inside the
// 8 column-steps. Wave 0 publishes lbuf/perm/livef; raw pivot rows stashed
// into Ubuf (merged araw) during factor. 3 barriers/panel (was 10).
__global__ __launch_bounds__(512, 2) void det_lu_kernel(
    const float* __restrict__ x,
    const float* __restrict__ F,
    float* __restrict__ out) {
  __shared__ __align__(16) float pcT[256 * 13];   // panel cols, row-major pad 13
  __shared__ __align__(16) float lbuf[8 * 256];   // multipliers per step
  __shared__ __align__(16) float Ubuf[8 * 260];   // raw-then-final pivot rows
  __shared__ float livef[256];
  __shared__ int   perm[256];
  __shared__ int   upbuf[256];
  __shared__ int   dnbuf[256];
  __shared__ int   wavecnt[8];
  __shared__ int   totinv;
  __shared__ float ldspad[12100];   // LDS > 80KiB -> exactly 1 block/CU

  const int tid = threadIdx.x;
  const int L   = tid & 63;       // lane
  const int w   = tid >> 6;       // wave, owns cols [32w, 32w+32)

  const float* xrow = x + (size_t)blockIdx.x * NN;

  // keep ldspad referenced (opaque never-true condition)
  if ((int)blockIdx.x < 0) ((volatile float*)ldspad)[tid] = 1.0f;

  // ---- rank the +/-1 pattern: up = x>0 positions, dn = x<=0 positions
  float xv = xrow[tid];            // 512 threads == NN
  bool pos = xv > 0.0f;
  unsigned long long mask = __ballot(pos);
  if (L == 0) wavecnt[w] = __popcll(mask);
  if (tid == 0) totinv = 0;
  if (tid < 256) livef[tid] = 1.0f;
  __syncthreads();
  {
    int base = 0;
    for (int i = 0; i < w; i++) base += wavecnt[i];
    int pbelow = __popcll(mask & ((1ull << L) - 1ull));
    if (pos) upbuf[base + pbelow] = tid;
    else     dnbuf[(64 * w - base) + (L - pbelow)] = tid;
  }
  __syncthreads();

  // ---- gather tile into 128 named scalars: aK_M = sub[L+64K][32w+M]
#define DECLC(M) const int cg##M = dnbuf[32 * w + (M)];
  T32S(DECLC)
  const int rg0 = upbuf[L];
  const int rg1 = upbuf[L + 64];
  const int rg2 = upbuf[L + 128];
  const int rg3 = upbuf[L + 192];
#define DECLA(K, M)                                                         \
  float a##K##_##M = (cg##M == rg##K)                                       \
      ? 0.0f                                                                \
      : F[(size_t)rg##K * NM1 + cg##M - (cg##M > rg##K ? 1 : 0)];
  T4x32(DECLA)

  // ---- seed panel 0: wave 0 writes PCT[row][0..7]
  if (w == 0) {
#define S0(K, M) if ((M) < 8) PCT(L + 64 * (K), (M)) = a##K##_##M;
    T4x32(S0)
  }
  double det = 1.0;
  __syncthreads();   // barrier A (panel 0 seeded)

  // ======================= panel factor-step machinery =====================
#define BC(J, S)                                                            \
    float uv##J = 0.0f;                                                     \
    if ((J) >= (S)) {                                                       \
      float _src = (kp == 0) ? pr0_##J : (kp == 1) ? pr1_##J                \
                 : (kp == 2) ? pr2_##J : pr3_##J;                           \
      uv##J = __shfl(_src, lp);                                             \
    }
#define LSTEP(K, S)                                                         \
    float l##K = ((dead4 >> (K)) & 1u) ? 0.0f : pr##K##_##S * invp;         \
    pr##K##_##S = l##K;
#define UPD(K, J, S)                                                        \
    if ((J) > (S)) pr##K##_##J = fmaf(-l##K, uv##J, pr##K##_##J);
#define UPDJ(J, S) UPD(0,J,S) UPD(1,J,S) UPD(2,J,S) UPD(3,J,S)
#define STH(K, M) if (kp == (K)) Ubuf[sb + (M)] = a##K##_##M;
#define FSTEP(S) {                                                          \
    unsigned b0 = (dead4 & 1u) ? 0u                                         \
        : ((__float_as_uint(fabsf(pr0_##S)) & 0xFFFFFF00u) | (unsigned)L);  \
    unsigned b1 = (dead4 & 2u) ? 0u                                         \
        : ((__float_as_uint(fabsf(pr1_##S)) & 0xFFFFFF00u) | (unsigned)(L + 64)); \
    unsigned b2 = (dead4 & 4u) ? 0u                                         \
        : ((__float_as_uint(fabsf(pr2_##S)) & 0xFFFFFF00u) | (unsigned)(L + 128)); \
    unsigned b3 = (dead4 & 8u) ? 0u                                         \
        : ((__float_as_uint(fabsf(pr3_##S)) & 0xFFFFFF00u) | (unsigned)(L + 192)); \
    unsigned m01 = b0 > b1 ? b0 : b1, m23 = b2 > b3 ? b2 : b3;              \
    unsigned key = m01 > m23 ? m01 : m23;                                   \
    _Pragma("unroll") for (int off = 32; off; off >>= 1) {                  \
      unsigned o = (unsigned)__shfl_xor((int)key, off);                     \
      key = key > o ? key : o;                                              \
    }                                                                       \
    const int pv = (int)(key & 255u);                                       \
    pv##S = pv;                                                             \
    const int kp = pv >> 6, lp = pv & 63;                                   \
    if (lp == L) dead4 |= 1u << kp;                                         \
    BC(0,S) BC(1,S) BC(2,S) BC(3,S) BC(4,S) BC(5,S) BC(6,S) BC(7,S)        \
    const float piv = uv##S;                                                \
    det *= (double)piv;                                                     \
    const float invp = 1.0f / piv;                                          \
    LSTEP(0,S) LSTEP(1,S) LSTEP(2,S) LSTEP(3,S)                             \
    UPDJ(0,S) UPDJ(1,S) UPDJ(2,S) UPDJ(3,S)                                 \
    UPDJ(4,S) UPDJ(5,S) UPDJ(6,S) UPDJ(7,S)                                 \
    if (w == 0) {                                                           \
      lbuf[(S) * 256 + L      ] = l0;                                       \
      lbuf[(S) * 256 + L +  64] = l1;                                       \
      lbuf[(S) * 256 + L + 128] = l2;                                       \
      lbuf[(S) * 256 + L + 192] = l3;                                       \
      if (L == lp) livef[pv] = 0.0f;                                        \
      if (L == 0) perm[P * 8 + (S)] = pv;                                   \
    }                                                                       \
    if ((4 * w + 3 > P) && L == lp) {                                       \
      const int sb = (S) * 260 + 32 * w;                                    \
      T4x32(STH)                                                            \
    }                                                                       \
  }

  // ---- panel loop
#pragma unroll 1
  for (int P = 0; P < 32; P++) {
    // load panel into regs (all waves, redundant copy of all 256 rows)
#define LDP(K, J) float pr##K##_##J = PCT(L + 64 * (K), (J));
    P4x8(LDP)
    unsigned dead4 = 0u;
    int pv0, pv1, pv2, pv3, pv4, pv5, pv6, pv7;
    (void)pv0; (void)pv1; (void)pv2; (void)pv3;
    (void)pv4; (void)pv5; (void)pv6; (void)pv7;

    // -------- 8 in-register column-steps, NO barriers --------
    FSTEP(0) FSTEP(1) FSTEP(2) FSTEP(3)
    FSTEP(4) FSTEP(5) FSTEP(6) FSTEP(7)

    __syncthreads();   // barrier B: lbuf/perm/livef + Ubuf raw stash visible

    // -------- U-solve: Ubuf[t][j] = raw[t][j] - sum_{s<t} l[s][p_t]*U[s][j]
    if (tid < 256) {
      const int j = tid;
      float u[8];
#pragma unroll
      for (int t = 0; t < 8; t++) {
        int pt = perm[P * 8 + t];
        float acc = Ubuf[t * 260 + j];           // raw (stashed in factor)
#pragma unroll
        for (int s2 = 0; s2 < t; s2++) acc = fmaf(-lbuf[s2 * 256 + pt], u[s2], acc);
        u[t] = acc;
        Ubuf[t * 260 + j] = acc;                 // final
      }
    }
    __syncthreads();   // barrier C: Ubuf final visible

    // -------- rank-8 trailing update (quad at a time) + seed next panel ----
#define TUROW(K, A, B, C, D)                                                \
    a##K##_##A = fmaf(-lk##K, uq.x, a##K##_##A);                            \
    a##K##_##B = fmaf(-lk##K, uq.y, a##K##_##B);                            \
    a##K##_##C = fmaf(-lk##K, uq.z, a##K##_##C);                            \
    a##K##_##D = fmaf(-lk##K, uq.w, a##K##_##D);
#define TUQ(A, B, C, D)                                                     \
    TUROW(0, A, B, C, D) TUROW(1, A, B, C, D)                               \
    TUROW(2, A, B, C, D) TUROW(3, A, B, C, D)
    if (4 * w + 3 > P) {
#pragma unroll 1
      for (int t = 0; t < 8; t++) {
        const int lb = t * 256 + L;
        const float lk0 = lbuf[lb];
        const float lk1 = lbuf[lb + 64];
        const float lk2 = lbuf[lb + 128];
        const float lk3 = lbuf[lb + 192];
        const float* ub = &Ubuf[t * 260 + 32 * w];
        { const float4 uq = *reinterpret_cast<const float4*>(ub + 0);
          TUQ(0, 1, 2, 3) }
        { const float4 uq = *reinterpret_cast<const float4*>(ub + 4);
          TUQ(4, 5, 6, 7) }
        { const float4 uq = *reinterpret_cast<const float4*>(ub + 8);
          TUQ(8, 9, 10, 11) }
        { const float4 uq = *reinterpret_cast<const float4*>(ub + 12);
          TUQ(12, 13, 14, 15) }
        { const float4 uq = *reinterpret_cast<const float4*>(ub + 16);
          TUQ(16, 17, 18, 19) }
        { const float4 uq = *reinterpret_cast<const float4*>(ub + 20);
          TUQ(20, 21, 22, 23) }
        { const float4 uq = *reinterpret_cast<const float4*>(ub + 24);
          TUQ(24, 25, 26, 27) }
        { const float4 uq = *reinterpret_cast<const float4*>(ub + 28);
          TUQ(28, 29, 30, 31) }
      }
    }
    {
      const int wstar = (P + 1) >> 2, h = (P + 1) & 3;
      if (P < 31 && w == wstar) {
        const float lv0 = livef[L];
        const float lv1 = livef[L + 64];
        const float lv2 = livef[L + 128];
        const float lv3 = livef[L + 192];
#define SEa(K, M) if ((M) < 8)                PCT(L + 64*(K), (M))      = a##K##_##M * lv##K;
#define SEb(K, M) if ((M) >= 8 && (M) < 16)   PCT(L + 64*(K), (M) - 8)  = a##K##_##M * lv##K;
#define SEc(K, M) if ((M) >= 16 && (M) < 24)  PCT(L + 64*(K), (M) - 16) = a##K##_##M * lv##K;
#define SEd(K, M) if ((M) >= 24)              PCT(L + 64*(K), (M) - 24) = a##K##_##M * lv##K;
        if (h == 0)      { T4x32(SEa) }
        else if (h == 1) { T4x32(SEb) }
        else if (h == 2) { T4x32(SEc) }
        else             { T4x32(SEd) }
      }
    }
    __syncthreads();   // barrier A (next panel seeded)
  }

  // ---- permutation parity via parallel inversion count (512-thread map)
  int myinv = 0;
  {
    const int i0 = tid & 255;
    const int cbase = (tid >> 8) * 128;
    const int pi = perm[i0];
#pragma unroll 8
    for (int j = 0; j < 128; j++) {
      int jj = cbase + j;
      if (jj > i0 && perm[jj] < pi) myinv++;
    }
  }
#pragma unroll
  for (int off = 32; off; off >>= 1) myinv += __shfl_xor(myinv, off);
  if (L == 0) atomicAdd(&totinv, myinv);
  __syncthreads();
  if (tid == 0) out[blockIdx.x] = (float)((totinv & 1) ? -det : det);
}

extern "C" void kernel_launch(void* const* d_in, const int* in_sizes, int n_in,
                              void* d_out, int out_size, void* d_ws, size_t ws_size,
                              hipStream_t stream) {
  const float* x = (const float*)d_in[0];   // (1024, 512) fp32
  const float* F = (const float*)d_in[1];   // (512*512-512,) fp32
  float* out = (float*)d_out;               // (1024,) fp32
  const int B = out_size;                   // 1024
  hipLaunchKernelGGL(det_lu_kernel, dim3(B), dim3(512), 0, stream, x, F, out);
}

// Round 11
// 1050.514 us; speedup vs baseline: 2.2354x; 1.2271x over previous
//
#include <hip/hip_runtime.h>

#define NN 512
#define NM1 511
#define PCT(r, j) pcT[(r) * 13 + (j)]

// X-macros: T4x32(X) expands X(K,M) for K=0..3 (row group), M=0..31 (col)
#define T32(X, K) X(K,0) X(K,1) X(K,2) X(K,3) X(K,4) X(K,5) X(K,6) X(K,7) \
  X(K,8) X(K,9) X(K,10) X(K,11) X(K,12) X(K,13) X(K,14) X(K,15) \
  X(K,16) X(K,17) X(K,18) X(K,19) X(K,20) X(K,21) X(K,22) X(K,23) \
  X(K,24) X(K,25) X(K,26) X(K,27) X(K,28) X(K,29) X(K,30) X(K,31)
#define T4x32(X) T32(X,0) T32(X,1) T32(X,2) T32(X,3)
#define T32S(X) X(0) X(1) X(2) X(3) X(4) X(5) X(6) X(7) \
  X(8) X(9) X(10) X(11) X(12) X(13) X(14) X(15) \
  X(16) X(17) X(18) X(19) X(20) X(21) X(22) X(23) \
  X(24) X(25) X(26) X(27) X(28) X(29) X(30) X(31)
#define P8(X, K) X(K,0) X(K,1) X(K,2) X(K,3) X(K,4) X(K,5) X(K,6) X(K,7)
#define P4x8(X) P8(X,0) P8(X,1) P8(X,2) P8(X,3)

// readlane: value of v at (uniform) lane l -> scalar
__device__ __forceinline__ float rdlane(float v, int l) {
  return __uint_as_float(
      (unsigned)__builtin_amdgcn_readlane((int)__float_as_uint(v), l));
}

// One block per matrix (1024 blocks), 512 threads (8 waves), 1 block/CU via
// LDS pad -> 256-reg/thread budget (r9/r10: no spill). Blocked LU, panel r=8,
// redundant in-register panel factorization (r10 structure, 3 barriers/panel).
// r11: LDS-pipe diet — r10 was LDS-pipe-bound (shfl==ds_bpermute):
//  (1) argmax reduce via DPP (row_shr 1/2/4/8 + row_bcast15/31 + readlane 63)
//      -> VALU pipe, no bpermute;
//  (2) pivot-row broadcast via v_readlane into SGPRs under uniform kp branch
//      -> no bpermute;
//  (3) pivot-row stash as 8x ds_write_b128 instead of 32x ds_write_b32.
__global__ __launch_bounds__(512, 2) void det_lu_kernel(
    const float* __restrict__ x,
    const float* __restrict__ F,
    float* __restrict__ out) {
  __shared__ __align__(16) float pcT[256 * 13];   // panel cols, row-major pad 13
  __shared__ __align__(16) float lbuf[8 * 256];   // multipliers per step
  __shared__ __align__(16) float Ubuf[8 * 260];   // raw-then-final pivot rows
  __shared__ float livef[256];
  __shared__ int   perm[256];
  __shared__ int   upbuf[256];
  __shared__ int   dnbuf[256];
  __shared__ int   wavecnt[8];
  __shared__ int   totinv;
  __shared__ float ldspad[12100];   // LDS > 80KiB -> exactly 1 block/CU

  const int tid = threadIdx.x;
  const int L   = tid & 63;       // lane
  const int w   = tid >> 6;       // wave, owns cols [32w, 32w+32)

  const float* xrow = x + (size_t)blockIdx.x * NN;

  // keep ldspad referenced (opaque never-true condition)
  if ((int)blockIdx.x < 0) ((volatile float*)ldspad)[tid] = 1.0f;

  // ---- rank the +/-1 pattern: up = x>0 positions, dn = x<=0 positions
  float xv = xrow[tid];            // 512 threads == NN
  bool pos = xv > 0.0f;
  unsigned long long mask = __ballot(pos);
  if (L == 0) wavecnt[w] = __popcll(mask);
  if (tid == 0) totinv = 0;
  if (tid < 256) livef[tid] = 1.0f;
  __syncthreads();
  {
    int base = 0;
    for (int i = 0; i < w; i++) base += wavecnt[i];
    int pbelow = __popcll(mask & ((1ull << L) - 1ull));
    if (pos) upbuf[base + pbelow] = tid;
    else     dnbuf[(64 * w - base) + (L - pbelow)] = tid;
  }
  __syncthreads();

  // ---- gather tile into 128 named scalars: aK_M = sub[L+64K][32w+M]
#define DECLC(M) const int cg##M = dnbuf[32 * w + (M)];
  T32S(DECLC)
  const int rg0 = upbuf[L];
  const int rg1 = upbuf[L + 64];
  const int rg2 = upbuf[L + 128];
  const int rg3 = upbuf[L + 192];
#define DECLA(K, M)                                                         \
  float a##K##_##M = (cg##M == rg##K)                                       \
      ? 0.0f                                                                \
      : F[(size_t)rg##K * NM1 + cg##M - (cg##M > rg##K ? 1 : 0)];
  T4x32(DECLA)

  // ---- seed panel 0: wave 0 writes PCT[row][0..7]
  if (w == 0) {
#define S0(K, M) if ((M) < 8) PCT(L + 64 * (K), (M)) = a##K##_##M;
    T4x32(S0)
  }
  double det = 1.0;
  __syncthreads();   // barrier A (panel 0 seeded)

  // ======================= panel factor-step machinery =====================
#define DPPMAX(CTRL) {                                                      \
    unsigned _t = (unsigned)__builtin_amdgcn_update_dpp(                    \
        0, (int)key, (CTRL), 0xf, 0xf, false);                              \
    key = key > _t ? key : _t; }
#define BCJ(K, J, S) if ((J) >= (S)) uv##J = rdlane(pr##K##_##J, lp);
#define BCARM(K, S)                                                         \
    if (kp == (K)) { BCJ(K,0,S) BCJ(K,1,S) BCJ(K,2,S) BCJ(K,3,S)            \
                     BCJ(K,4,S) BCJ(K,5,S) BCJ(K,6,S) BCJ(K,7,S) }
#define LSTEP(K, S)                                                         \
    float l##K = ((dead4 >> (K)) & 1u) ? 0.0f : pr##K##_##S * invp;         \
    pr##K##_##S = l##K;
#define UPD(K, J, S)                                                        \
    if ((J) > (S)) pr##K##_##J = fmaf(-l##K, uv##J, pr##K##_##J);
#define UPDJ(J, S) UPD(0,J,S) UPD(1,J,S) UPD(2,J,S) UPD(3,J,S)
#define STQ(K, Q, M0, M1, M2, M3)                                           \
    if (kp == (K)) *reinterpret_cast<float4*>(&Ubuf[sb + 4 * (Q)]) =        \
        make_float4(a##K##_##M0, a##K##_##M1, a##K##_##M2, a##K##_##M3);
#define STHK(K)                                                             \
    STQ(K,0,0,1,2,3) STQ(K,1,4,5,6,7) STQ(K,2,8,9,10,11)                    \
    STQ(K,3,12,13,14,15) STQ(K,4,16,17,18,19) STQ(K,5,20,21,22,23)          \
    STQ(K,6,24,25,26,27) STQ(K,7,28,29,30,31)
#define FSTEP(S) {                                                          \
    unsigned b0 = (dead4 & 1u) ? 0u                                         \
        : ((__float_as_uint(fabsf(pr0_##S)) & 0xFFFFFF00u) | (unsigned)L);  \
    unsigned b1 = (dead4 & 2u) ? 0u                                         \
        : ((__float_as_uint(fabsf(pr1_##S)) & 0xFFFFFF00u) | (unsigned)(L + 64)); \
    unsigned b2 = (dead4 & 4u) ? 0u                                         \
        : ((__float_as_uint(fabsf(pr2_##S)) & 0xFFFFFF00u) | (unsigned)(L + 128)); \
    unsigned b3 = (dead4 & 8u) ? 0u                                         \
        : ((__float_as_uint(fabsf(pr3_##S)) & 0xFFFFFF00u) | (unsigned)(L + 192)); \
    unsigned m01 = b0 > b1 ? b0 : b1, m23 = b2 > b3 ? b2 : b3;              \
    unsigned key = m01 > m23 ? m01 : m23;                                   \
    DPPMAX(0x111) DPPMAX(0x112) DPPMAX(0x114) DPPMAX(0x118)                 \
    DPPMAX(0x142) DPPMAX(0x143)                                             \
    const int pv = __builtin_amdgcn_readlane((int)key, 63) & 255;           \
    const int kp = pv >> 6, lp = pv & 63;                                   \
    if (lp == L) dead4 |= 1u << kp;                                         \
    float uv0 = 0.f, uv1 = 0.f, uv2 = 0.f, uv3 = 0.f;                       \
    float uv4 = 0.f, uv5 = 0.f, uv6 = 0.f, uv7 = 0.f;                       \
    BCARM(0,S) BCARM(1,S) BCARM(2,S) BCARM(3,S)                             \
    const float piv = uv##S;                                                \
    det *= (double)piv;                                                     \
    const float invp = 1.0f / piv;                                          \
    LSTEP(0,S) LSTEP(1,S) LSTEP(2,S) LSTEP(3,S)                             \
    UPDJ(0,S) UPDJ(1,S) UPDJ(2,S) UPDJ(3,S)                                 \
    UPDJ(4,S) UPDJ(5,S) UPDJ(6,S) UPDJ(7,S)                                 \
    if (w == 0) {                                                           \
      lbuf[(S) * 256 + L      ] = l0;                                       \
      lbuf[(S) * 256 + L +  64] = l1;                                       \
      lbuf[(S) * 256 + L + 128] = l2;                                       \
      lbuf[(S) * 256 + L + 192] = l3;                                       \
      if (L == lp) livef[pv] = 0.0f;                                        \
      if (L == 0) perm[P * 8 + (S)] = pv;                                   \
    }                                                                       \
    if ((4 * w + 3 > P) && L == lp) {                                       \
      const int sb = (S) * 260 + 32 * w;                                    \
      STHK(0) STHK(1) STHK(2) STHK(3)                                       \
    }                                                                       \
  }

  // ---- panel loop
#pragma unroll 1
  for (int P = 0; P < 32; P++) {
    // load panel into regs (all waves, redundant copy of all 256 rows)
#define LDP(K, J) float pr##K##_##J = PCT(L + 64 * (K), (J));
    P4x8(LDP)
    unsigned dead4 = 0u;

    // -------- 8 in-register column-steps, NO barriers, NO bpermute --------
    FSTEP(0) FSTEP(1) FSTEP(2) FSTEP(3)
    FSTEP(4) FSTEP(5) FSTEP(6) FSTEP(7)

    __syncthreads();   // barrier B: lbuf/perm/livef + Ubuf raw stash visible

    // -------- U-solve: Ubuf[t][j] = raw[t][j] - sum_{s<t} l[s][p_t]*U[s][j]
    if (tid < 256) {
      const int j = tid;
      float u[8];
#pragma unroll
      for (int t = 0; t < 8; t++) {
        int pt = perm[P * 8 + t];
        float acc = Ubuf[t * 260 + j];           // raw (stashed in factor)
#pragma unroll
        for (int s2 = 0; s2 < t; s2++) acc = fmaf(-lbuf[s2 * 256 + pt], u[s2], acc);
        u[t] = acc;
        Ubuf[t * 260 + j] = acc;                 // final
      }
    }
    __syncthreads();   // barrier C: Ubuf final visible

    // -------- rank-8 trailing update (quad at a time) + seed next panel ----
#define TUROW(K, A, B, C, D)                                                \
    a##K##_##A = fmaf(-lk##K, uq.x, a##K##_##A);                            \
    a##K##_##B = fmaf(-lk##K, uq.y, a##K##_##B);                            \
    a##K##_##C = fmaf(-lk##K, uq.z, a##K##_##C);                            \
    a##K##_##D = fmaf(-lk##K, uq.w, a##K##_##D);
#define TUQ(A, B, C, D)                                                     \
    TUROW(0, A, B, C, D) TUROW(1, A, B, C, D)                               \
    TUROW(2, A, B, C, D) TUROW(3, A, B, C, D)
    if (4 * w + 3 > P) {
#pragma unroll 1
      for (int t = 0; t < 8; t++) {
        const int lb = t * 256 + L;
        const float lk0 = lbuf[lb];
        const float lk1 = lbuf[lb + 64];
        const float lk2 = lbuf[lb + 128];
        const float lk3 = lbuf[lb + 192];
        const float* ub = &Ubuf[t * 260 + 32 * w];
        { const float4 uq = *reinterpret_cast<const float4*>(ub + 0);
          TUQ(0, 1, 2, 3) }
        { const float4 uq = *reinterpret_cast<const float4*>(ub + 4);
          TUQ(4, 5, 6, 7) }
        { const float4 uq = *reinterpret_cast<const float4*>(ub + 8);
          TUQ(8, 9, 10, 11) }
        { const float4 uq = *reinterpret_cast<const float4*>(ub + 12);
          TUQ(12, 13, 14, 15) }
        { const float4 uq = *reinterpret_cast<const float4*>(ub + 16);
          TUQ(16, 17, 18, 19) }
        { const float4 uq = *reinterpret_cast<const float4*>(ub + 20);
          TUQ(20, 21, 22, 23) }
        { const float4 uq = *reinterpret_cast<const float4*>(ub + 24);
          TUQ(24, 25, 26, 27) }
        { const float4 uq = *reinterpret_cast<const float4*>(ub + 28);
          TUQ(28, 29, 30, 31) }
      }
    }
    {
      const int wstar = (P + 1) >> 2, h = (P + 1) & 3;
      if (P < 31 && w == wstar) {
        const float lv0 = livef[L];
        const float lv1 = livef[L + 64];
        const float lv2 = livef[L + 128];
        const float lv3 = livef[L + 192];
#define SEa(K, M) if ((M) < 8)                PCT(L + 64*(K), (M))      = a##K##_##M * lv##K;
#define SEb(K, M) if ((M) >= 8 && (M) < 16)   PCT(L + 64*(K), (M) - 8)  = a##K##_##M * lv##K;
#define SEc(K, M) if ((M) >= 16 && (M) < 24)  PCT(L + 64*(K), (M) - 16) = a##K##_##M * lv##K;
#define SEd(K, M) if ((M) >= 24)              PCT(L + 64*(K), (M) - 24) = a##K##_##M * lv##K;
        if (h == 0)      { T4x32(SEa) }
        else if (h == 1) { T4x32(SEb) }
        else if (h == 2) { T4x32(SEc) }
        else             { T4x32(SEd) }
      }
    }
    __syncthreads();   // barrier A (next panel seeded)
  }

  // ---- permutation parity via parallel inversion count (512-thread map)
  int myinv = 0;
  {
    const int i0 = tid & 255;
    const int cbase = (tid >> 8) * 128;
    const int pi = perm[i0];
#pragma unroll 8
    for (int j = 0; j < 128; j++) {
      int jj = cbase + j;
      if (jj > i0 && perm[jj] < pi) myinv++;
    }
  }
#pragma unroll
  for (int off = 32; off; off >>= 1) myinv += __shfl_xor(myinv, off);
  if (L == 0) atomicAdd(&totinv, myinv);
  __syncthreads();
  if (tid == 0) out[blockIdx.x] = (float)((totinv & 1) ? -det : det);
}

extern "C" void kernel_launch(void* const* d_in, const int* in_sizes, int n_in,
                              void* d_out, int out_size, void* d_ws, size_t ws_size,
                              hipStream_t stream) {
  const float* x = (const float*)d_in[0];   // (1024, 512) fp32
  const float* F = (const float*)d_in[1];   // (512*512-512,) fp32
  float* out = (float*)d_out;               // (1024,) fp32
  const int B = out_size;                   // 1024
  hipLaunchKernelGGL(det_lu_kernel, dim3(B), dim3(512), 0, stream, x, F, out);
}